// Round 5
// baseline (441.854 us; speedup 1.0000x reference)
//
#include <hip/hip_runtime.h>
#include <hip/hip_bf16.h>

#define N_NODES 50000
#define N_EDGES 800000
#define HID 128

typedef __bf16 bf16x8 __attribute__((ext_vector_type(8)));
typedef float f32x4 __attribute__((ext_vector_type(4)));

// ---------------------------------------------------------------------------
// prep: blocks [0,256) repack weights into MFMA-B-fragment-major bf16;
//       blocks [256,...) histogram edge dst.
// Wsw[m][((kstep*8+ntile)*64+lane)*8+j] = W_m[kstep*32+(lane>>4)*8+j][ntile*16+(lane&15)]
// m=0: W_in, m=1: W1[:128] (dst half), m=2: W1[128:] (src half), m=3: W2
// ---------------------------------------------------------------------------
__global__ __launch_bounds__(256) void prep_kernel(
    const float* __restrict__ Win, const float* __restrict__ W1,
    const float* __restrict__ W2, __bf16* __restrict__ Wsw,
    const int* __restrict__ eidx, int* __restrict__ hist)
{
    int b = blockIdx.x;
    int tid = threadIdx.x;
    if (b < 256) {
        int id = b * 256 + tid;   // 0..65535
        int m     = id >> 14;
        int rem   = id & 16383;
        int j     = rem & 7;
        int lane  = (rem >> 3) & 63;
        int ntile = (rem >> 9) & 7;
        int kstep = rem >> 12;
        int k = kstep * 32 + (lane >> 4) * 8 + j;
        int n = ntile * 16 + (lane & 15);
        float v;
        if (m == 0)      v = Win[k * HID + n];
        else if (m == 1) v = W1[k * HID + n];
        else if (m == 2) v = W1[(k + HID) * HID + n];
        else             v = W2[k * HID + n];
        Wsw[id] = (__bf16)v;
    } else {
        int e = (b - 256) * 256 + tid;
        if (e < N_EDGES) atomicAdd(&hist[eidx[N_EDGES + e]], 1);
    }
}

// ---------------------------------------------------------------------------
// h = relu(x @ W_in + b_in), x f32 staged to bf16 LDS, h stored bf16.
// ---------------------------------------------------------------------------
__global__ __launch_bounds__(256) void proj_kernel(
    const float* __restrict__ x, const __bf16* __restrict__ Wsw,
    const float* __restrict__ b_in, __bf16* __restrict__ h)
{
    __shared__ __bf16 At[128][136];
    int tid = threadIdx.x;
    int wave = tid >> 6, lane = tid & 63;
    int m0 = blockIdx.x * 128;

    for (int i = tid; i < 128 * 32; i += 256) {
        int r = i >> 5, c = i & 31;
        int row = m0 + r;
        float4 v = make_float4(0.f, 0.f, 0.f, 0.f);
        if (row < N_NODES) v = *(const float4*)(x + (long)row * HID + c * 4);
        __bf16* dst = &At[r][c * 4];
        dst[0] = (__bf16)v.x; dst[1] = (__bf16)v.y;
        dst[2] = (__bf16)v.z; dst[3] = (__bf16)v.w;
    }
    __syncthreads();

    f32x4 acc[2][8] = {};
    int r_lane = lane & 15, quad = lane >> 4;
#pragma unroll
    for (int ks = 0; ks < 4; ++ks) {
        int kb = ks * 32 + quad * 8;
        bf16x8 a0 = *(const bf16x8*)(&At[wave * 32 + r_lane][kb]);
        bf16x8 a1 = *(const bf16x8*)(&At[wave * 32 + 16 + r_lane][kb]);
#pragma unroll
        for (int n = 0; n < 8; ++n) {
            bf16x8 b = *(const bf16x8*)(Wsw + ((ks * 8 + n) * 64 + lane) * 8);
            acc[0][n] = __builtin_amdgcn_mfma_f32_16x16x32_bf16(a0, b, acc[0][n], 0, 0, 0);
            acc[1][n] = __builtin_amdgcn_mfma_f32_16x16x32_bf16(a1, b, acc[1][n], 0, 0, 0);
        }
    }
#pragma unroll
    for (int n = 0; n < 8; ++n) {
        int col = n * 16 + r_lane;
        float bias = b_in[col];
#pragma unroll
        for (int mt = 0; mt < 2; ++mt) {
            int rbase = m0 + wave * 32 + mt * 16 + quad * 4;
#pragma unroll
            for (int r = 0; r < 4; ++r) {
                int row = rbase + r;
                if (row < N_NODES) {
                    float v = acc[mt][n][r] + bias;
                    h[(long)row * HID + col] = (__bf16)(v > 0.f ? v : 0.f);
                }
            }
        }
    }
}

// ---------------------------------------------------------------------------
// scan1: single-block exclusive scan of hist[0..N_NODES) -> cursor
// ---------------------------------------------------------------------------
#define SCAN_PER 49   // 1024*49 = 50176 >= 50000
__global__ __launch_bounds__(1024) void scan1(
    const int* __restrict__ hist, int* __restrict__ cursor)
{
    __shared__ int ps[1024];
    int t = threadIdx.x;
    int base = t * SCAN_PER;
    int s = 0;
    for (int j = 0; j < SCAN_PER; ++j) {
        int i = base + j;
        if (i < N_NODES) s += hist[i];
    }
    ps[t] = s;
    __syncthreads();
    for (int d = 1; d < 1024; d <<= 1) {
        int v = (t >= d) ? ps[t - d] : 0;
        __syncthreads();
        ps[t] += v;
        __syncthreads();
    }
    int run = ps[t] - s;   // exclusive prefix for this thread's range
    for (int j = 0; j < SCAN_PER; ++j) {
        int i = base + j;
        if (i < N_NODES) {
            int hv = hist[i];
            cursor[i] = run;
            run += hv;
        }
    }
}

// permute: scatter edges into dst-sorted order as int2 (src,dst)
__global__ __launch_bounds__(256) void permute_kernel(
    const int* __restrict__ eidx, int* __restrict__ cursor, int2* __restrict__ es)
{
    int e = blockIdx.x * 256 + threadIdx.x;
    if (e < N_EDGES) {
        int d = eidx[N_EDGES + e];
        int pos = atomicAdd(&cursor[d], 1);
        es[pos] = make_int2(eidx[e], d);
    }
}

// ---------------------------------------------------------------------------
// Edge stage-1 on dst-sorted edges, all-register:
//   t_e = relu( h[dst]@W1a + h[src]@W1b + b1 )   (C-layout registers, f32)
//   segmented reduce in C-layout: wave-uniform boundary-mask loop,
//   predicated adds + shfl_xor(16/32), quad-0 lanes flush atomics into Tagg.
// N processed in two halves of 64 cols to keep acc at 32 regs (occupancy).
// ---------------------------------------------------------------------------
__global__ __launch_bounds__(256, 5) void edge1_kernel(
    const __bf16* __restrict__ h, const int2* __restrict__ es,
    const __bf16* __restrict__ Wsw, const float* __restrict__ b1,
    float* __restrict__ Tagg)
{
    __shared__ int ssrc[128];
    __shared__ int sdst[128];

    int tid = threadIdx.x;
    int wave = tid >> 6, lane = tid & 63;
    int e0 = blockIdx.x * 128;

    if (tid < 128) {
        int2 e = es[e0 + tid];
        ssrc[tid] = e.x;
        sdst[tid] = e.y;
    }
    __syncthreads();

    // per-wave boundary mask: bit i = (row wave*32+i) starts a new segment
    int li = lane & 31;
    int ri = wave * 32 + li;
    bool f = (lane < 32) && (ri > 0) && (sdst[ri] != sdst[ri - 1]);
    unsigned int bmask = (unsigned int)__ballot(f);

    const __bf16* W1a = Wsw + 16384;
    const __bf16* W1b = Wsw + 32768;
    int r_lane = lane & 15, quad = lane >> 4;

    // prefetch row indices for gathers (rows wave*32 + mt*16 + r_lane)
    long rd0 = (long)sdst[wave * 32 + r_lane] * HID;
    long rs0 = (long)ssrc[wave * 32 + r_lane] * HID;
    long rd1 = (long)sdst[wave * 32 + 16 + r_lane] * HID;
    long rs1 = (long)ssrc[wave * 32 + 16 + r_lane] * HID;

#pragma unroll
    for (int half = 0; half < 2; ++half) {
        f32x4 acc[2][4] = {};
#pragma unroll
        for (int ks = 0; ks < 4; ++ks) {
            int kb = ks * 32 + quad * 8;
            bf16x8 ad0 = *(const bf16x8*)(h + rd0 + kb);
            bf16x8 as0 = *(const bf16x8*)(h + rs0 + kb);
            bf16x8 ad1 = *(const bf16x8*)(h + rd1 + kb);
            bf16x8 as1 = *(const bf16x8*)(h + rs1 + kb);
#pragma unroll
            for (int n = 0; n < 4; ++n) {
                int nn = half * 4 + n;
                bf16x8 b_d = *(const bf16x8*)(W1a + ((ks * 8 + nn) * 64 + lane) * 8);
                bf16x8 b_s = *(const bf16x8*)(W1b + ((ks * 8 + nn) * 64 + lane) * 8);
                acc[0][n] = __builtin_amdgcn_mfma_f32_16x16x32_bf16(ad0, b_d, acc[0][n], 0, 0, 0);
                acc[0][n] = __builtin_amdgcn_mfma_f32_16x16x32_bf16(as0, b_s, acc[0][n], 0, 0, 0);
                acc[1][n] = __builtin_amdgcn_mfma_f32_16x16x32_bf16(ad1, b_d, acc[1][n], 0, 0, 0);
                acc[1][n] = __builtin_amdgcn_mfma_f32_16x16x32_bf16(as1, b_s, acc[1][n], 0, 0, 0);
            }
        }

        // bias + relu in-register
#pragma unroll
        for (int n = 0; n < 4; ++n) {
            float bias = b1[(half * 4 + n) * 16 + r_lane];
#pragma unroll
            for (int mt = 0; mt < 2; ++mt)
#pragma unroll
                for (int r = 0; r < 4; ++r) {
                    float v = acc[mt][n][r] + bias;
                    acc[mt][n][r] = v > 0.f ? v : 0.f;
                }
        }

        // segmented reduce over this wave's 32 rows (wave-uniform loop)
        unsigned int rem = bmask & ~1u;
        int a = 0;
        for (;;) {
            int bnd = rem ? (__ffs(rem) - 1) : 32;
            bool p[2][4];
#pragma unroll
            for (int mt = 0; mt < 2; ++mt)
#pragma unroll
                for (int r = 0; r < 4; ++r) {
                    int row = mt * 16 + quad * 4 + r;
                    p[mt][r] = (row >= a) && (row < bnd);
                }
            long dbase = (long)sdst[wave * 32 + a] * HID;
#pragma unroll
            for (int n = 0; n < 4; ++n) {
                float s = 0.f;
#pragma unroll
                for (int mt = 0; mt < 2; ++mt)
#pragma unroll
                    for (int r = 0; r < 4; ++r)
                        s += p[mt][r] ? acc[mt][n][r] : 0.f;
                s += __shfl_xor(s, 16);
                s += __shfl_xor(s, 32);
                if (lane < 16)
                    atomicAdd(&Tagg[dbase + (half * 4 + n) * 16 + r_lane], s);
            }
            if (bnd >= 32) break;
            a = bnd;
            rem &= rem - 1;
        }
    }
}

// ---------------------------------------------------------------------------
// Node finish: h2 = relu(Tagg @ W2 + deg*b2); out = h2 @ Wc + bc (fused).
// ---------------------------------------------------------------------------
__global__ __launch_bounds__(256) void node_kernel(
    const float* __restrict__ Tagg, const __bf16* __restrict__ Wsw,
    const int* __restrict__ hist, const float* __restrict__ b2,
    const float* __restrict__ Wc, const float* __restrict__ bc,
    float* __restrict__ out)
{
    __shared__ __bf16 At[128][136];
    int tid = threadIdx.x;
    int wave = tid >> 6, lane = tid & 63;
    int m0 = blockIdx.x * 128;

    for (int i = tid; i < 128 * 32; i += 256) {
        int r = i >> 5, c = i & 31;
        int row = m0 + r;
        float4 v = make_float4(0.f, 0.f, 0.f, 0.f);
        if (row < N_NODES) v = *(const float4*)(Tagg + (long)row * HID + c * 4);
        __bf16* dst = &At[r][c * 4];
        dst[0] = (__bf16)v.x; dst[1] = (__bf16)v.y;
        dst[2] = (__bf16)v.z; dst[3] = (__bf16)v.w;
    }
    __syncthreads();

    const __bf16* W2f = Wsw + 49152;
    f32x4 acc[2][8] = {};
    int r_lane = lane & 15, quad = lane >> 4;
#pragma unroll
    for (int ks = 0; ks < 4; ++ks) {
        int kb = ks * 32 + quad * 8;
        bf16x8 a0 = *(const bf16x8*)(&At[wave * 32 + r_lane][kb]);
        bf16x8 a1 = *(const bf16x8*)(&At[wave * 32 + 16 + r_lane][kb]);
#pragma unroll
        for (int n = 0; n < 8; ++n) {
            bf16x8 b = *(const bf16x8*)(W2f + ((ks * 8 + n) * 64 + lane) * 8);
            acc[0][n] = __builtin_amdgcn_mfma_f32_16x16x32_bf16(a0, b, acc[0][n], 0, 0, 0);
            acc[1][n] = __builtin_amdgcn_mfma_f32_16x16x32_bf16(a1, b, acc[1][n], 0, 0, 0);
        }
    }

#pragma unroll
    for (int mt = 0; mt < 2; ++mt) {
#pragma unroll
        for (int r = 0; r < 4; ++r) {
            int row = m0 + wave * 32 + mt * 16 + quad * 4 + r;
            float deg = (row < N_NODES) ? (float)hist[row] : 0.f;
            float s0 = 0.f, s1 = 0.f;
#pragma unroll
            for (int n = 0; n < 8; ++n) {
                int col = n * 16 + r_lane;
                float v = acc[mt][n][r] + deg * b2[col];
                v = v > 0.f ? v : 0.f;
                s0 += v * Wc[col * 2 + 0];
                s1 += v * Wc[col * 2 + 1];
            }
#pragma unroll
            for (int off = 1; off < 16; off <<= 1) {
                s0 += __shfl_xor(s0, off);
                s1 += __shfl_xor(s1, off);
            }
            if (r_lane == 0 && row < N_NODES) {
                out[(long)row * 2 + 0] = s0 + bc[0];
                out[(long)row * 2 + 1] = s1 + bc[1];
            }
        }
    }
}

extern "C" void kernel_launch(void* const* d_in, const int* in_sizes, int n_in,
                              void* d_out, int out_size, void* d_ws, size_t ws_size,
                              hipStream_t stream) {
    const float* x    = (const float*)d_in[0];
    const int* eidx   = (const int*)d_in[1];
    const float* W_in = (const float*)d_in[2];
    const float* b_in = (const float*)d_in[3];
    const float* W1   = (const float*)d_in[4];
    const float* b1   = (const float*)d_in[5];
    const float* W2   = (const float*)d_in[6];
    const float* b2   = (const float*)d_in[7];
    const float* Wc   = (const float*)d_in[8];
    const float* bc   = (const float*)d_in[9];
    float* out = (float*)d_out;

    char* ws = (char*)d_ws;
    __bf16* h   = (__bf16*)(ws + 0);              // 12,800,000
    float* Tagg = (float*)(ws + 12800000);        // 25,600,000
    int2* es    = (int2*)(ws + 38400000);         //  6,400,000
    int* hist   = (int*)(ws + 44800000);          //    200,000
    int* cursor = (int*)(ws + 45000000);          //    200,000
    __bf16* Wsw = (__bf16*)(ws + 45200000);       //    131,072

    hipMemsetAsync(hist, 0, (size_t)N_NODES * sizeof(int), stream);
    hipMemsetAsync(Tagg, 0, (size_t)N_NODES * HID * sizeof(float), stream);

    prep_kernel<<<256 + (N_EDGES + 255) / 256, 256, 0, stream>>>(W_in, W1, W2, Wsw, eidx, hist);
    proj_kernel<<<(N_NODES + 127) / 128, 256, 0, stream>>>(x, Wsw, b_in, h);
    scan1<<<1, 1024, 0, stream>>>(hist, cursor);
    permute_kernel<<<(N_EDGES + 255) / 256, 256, 0, stream>>>(eidx, cursor, es);
    edge1_kernel<<<N_EDGES / 128, 256, 0, stream>>>(h, es, Wsw, b1, Tagg);
    node_kernel<<<(N_NODES + 127) / 128, 256, 0, stream>>>(Tagg, Wsw, hist, b2, Wc, bc, out);
}

// Round 7
// 321.572 us; speedup vs baseline: 1.3740x; 1.3740x over previous
//
#include <hip/hip_runtime.h>
#include <hip/hip_bf16.h>

#define N_NODES 50000
#define N_EDGES 800000
#define HID 128
#define SCAN_B 196      // ceil(50000/256)

typedef __bf16 bf16x8 __attribute__((ext_vector_type(8)));
typedef float f32x4 __attribute__((ext_vector_type(4)));

// ---------------------------------------------------------------------------
// prep: blocks [0,256) repack weights into MFMA-B-fragment-major bf16;
//       blocks [256,...) histogram edge dst.
// Wsw[m][((kstep*8+ntile)*64+lane)*8+j] = W_m[kstep*32+(lane>>4)*8+j][ntile*16+(lane&15)]
// m=0: W_in, m=1: W1[:128] (dst half), m=2: W1[128:] (src half), m=3: W2
// ---------------------------------------------------------------------------
__global__ __launch_bounds__(256) void prep_kernel(
    const float* __restrict__ Win, const float* __restrict__ W1,
    const float* __restrict__ W2, __bf16* __restrict__ Wsw,
    const int* __restrict__ eidx, int* __restrict__ hist)
{
    int b = blockIdx.x;
    int tid = threadIdx.x;
    if (b < 256) {
        int id = b * 256 + tid;   // 0..65535
        int m     = id >> 14;
        int rem   = id & 16383;
        int j     = rem & 7;
        int lane  = (rem >> 3) & 63;
        int ntile = (rem >> 9) & 7;
        int kstep = rem >> 12;
        int k = kstep * 32 + (lane >> 4) * 8 + j;
        int n = ntile * 16 + (lane & 15);
        float v;
        if (m == 0)      v = Win[k * HID + n];
        else if (m == 1) v = W1[k * HID + n];
        else if (m == 2) v = W1[(k + HID) * HID + n];
        else             v = W2[k * HID + n];
        Wsw[id] = (__bf16)v;
    } else {
        int e = (b - 256) * 256 + tid;
        if (e < N_EDGES) atomicAdd(&hist[eidx[N_EDGES + e]], 1);
    }
}

// ---------------------------------------------------------------------------
// h = relu(x @ W_in + b_in), x f32 staged to bf16 LDS, h stored bf16.
// ---------------------------------------------------------------------------
__global__ __launch_bounds__(256) void proj_kernel(
    const float* __restrict__ x, const __bf16* __restrict__ Wsw,
    const float* __restrict__ b_in, __bf16* __restrict__ h)
{
    __shared__ __bf16 At[128][136];
    int tid = threadIdx.x;
    int wave = tid >> 6, lane = tid & 63;
    int m0 = blockIdx.x * 128;

    for (int i = tid; i < 128 * 32; i += 256) {
        int r = i >> 5, c = i & 31;
        int row = m0 + r;
        float4 v = make_float4(0.f, 0.f, 0.f, 0.f);
        if (row < N_NODES) v = *(const float4*)(x + (long)row * HID + c * 4);
        __bf16* dst = &At[r][c * 4];
        dst[0] = (__bf16)v.x; dst[1] = (__bf16)v.y;
        dst[2] = (__bf16)v.z; dst[3] = (__bf16)v.w;
    }
    __syncthreads();

    f32x4 acc[2][8] = {};
    int r_lane = lane & 15, quad = lane >> 4;
#pragma unroll
    for (int ks = 0; ks < 4; ++ks) {
        int kb = ks * 32 + quad * 8;
        bf16x8 a0 = *(const bf16x8*)(&At[wave * 32 + r_lane][kb]);
        bf16x8 a1 = *(const bf16x8*)(&At[wave * 32 + 16 + r_lane][kb]);
#pragma unroll
        for (int n = 0; n < 8; ++n) {
            bf16x8 b = *(const bf16x8*)(Wsw + ((ks * 8 + n) * 64 + lane) * 8);
            acc[0][n] = __builtin_amdgcn_mfma_f32_16x16x32_bf16(a0, b, acc[0][n], 0, 0, 0);
            acc[1][n] = __builtin_amdgcn_mfma_f32_16x16x32_bf16(a1, b, acc[1][n], 0, 0, 0);
        }
    }
#pragma unroll
    for (int n = 0; n < 8; ++n) {
        int col = n * 16 + r_lane;
        float bias = b_in[col];
#pragma unroll
        for (int mt = 0; mt < 2; ++mt) {
            int rbase = m0 + wave * 32 + mt * 16 + quad * 4;
#pragma unroll
            for (int r = 0; r < 4; ++r) {
                int row = rbase + r;
                if (row < N_NODES) {
                    float v = acc[mt][n][r] + bias;
                    h[(long)row * HID + col] = (__bf16)(v > 0.f ? v : 0.f);
                }
            }
        }
    }
}

// ---------------------------------------------------------------------------
// Parallel scan hierarchy: scan_a (per-block) -> scan_b (block sums) -> scan_c
// ---------------------------------------------------------------------------
__global__ __launch_bounds__(256) void scan_a(
    const int* __restrict__ hist, int* __restrict__ loc, int* __restrict__ bsum)
{
    __shared__ int s[256];
    int t = threadIdx.x;
    int i = blockIdx.x * 256 + t;
    int v = (i < N_NODES) ? hist[i] : 0;
    s[t] = v;
    __syncthreads();
    for (int d = 1; d < 256; d <<= 1) {
        int tv = (t >= d) ? s[t - d] : 0;
        __syncthreads();
        s[t] += tv;
        __syncthreads();
    }
    if (i < N_NODES) loc[i] = s[t] - v;
    if (t == 255) bsum[blockIdx.x] = s[255];
}

__global__ __launch_bounds__(256) void scan_b(int* __restrict__ bsum)
{
    __shared__ int s[256];
    int t = threadIdx.x;
    int v = (t < SCAN_B) ? bsum[t] : 0;
    s[t] = v;
    __syncthreads();
    for (int d = 1; d < 256; d <<= 1) {
        int tv = (t >= d) ? s[t - d] : 0;
        __syncthreads();
        s[t] += tv;
        __syncthreads();
    }
    if (t < SCAN_B) bsum[t] = s[t] - v;   // exclusive
}

__global__ __launch_bounds__(256) void scan_c(
    const int* __restrict__ loc, const int* __restrict__ bsum, int* __restrict__ cursor)
{
    int i = blockIdx.x * 256 + threadIdx.x;
    if (i < N_NODES) cursor[i] = loc[i] + bsum[blockIdx.x];
}

// permute: scatter edges into dst-sorted order as int2 (src,dst)
__global__ __launch_bounds__(256) void permute_kernel(
    const int* __restrict__ eidx, int* __restrict__ cursor, int2* __restrict__ es)
{
    int e = blockIdx.x * 256 + threadIdx.x;
    if (e < N_EDGES) {
        int d = eidx[N_EDGES + e];
        int pos = atomicAdd(&cursor[d], 1);
        es[pos] = make_int2(eidx[e], d);
    }
}

// ---------------------------------------------------------------------------
// Edge stage-1 v4 = R5's proven 256-thread/TILE-128 core + per-half LDS B.
// Per n-half (4 of 8 col-tiles): stage the 16 needed fragments of W1a and
// W1b (32 KB) into LDS between barriers, then MFMA reads B via ds_read_b128.
// Segmented reduce in C-layout registers (wave-uniform bitmask loop),
// quad-folded via shfl, lanes 0-15 flush f32 atomics into Tagg.
// LDS total: 32 KB sW + 1 KB indices.
// ---------------------------------------------------------------------------
__global__ __launch_bounds__(256, 4) void edge1_kernel(
    const __bf16* __restrict__ h, const int2* __restrict__ es,
    const __bf16* __restrict__ Wsw, const float* __restrict__ b1,
    float* __restrict__ Tagg)
{
    __shared__ uint4 sWq[2048];        // 32 KB: [m2][frag(ks*4+n)][lane] granules
    __shared__ int ssrc[128];
    __shared__ int sdst[128];

    int tid = threadIdx.x;
    int wave = tid >> 6, lane = tid & 63;
    int r_lane = lane & 15, quad = lane >> 4;
    int li = lane & 31;
    int e0 = blockIdx.x * 128;

    if (tid < 128) {
        int2 e = es[e0 + tid];
        ssrc[tid] = e.x;
        sdst[tid] = e.y;
    }
    __syncthreads();

    // per-wave boundary mask: bit i = (row wave*32+i) starts a new segment
    int ri = wave * 32 + li;
    bool f = (lane < 32) && (ri > 0) && (sdst[ri] != sdst[ri - 1]);
    unsigned int bmask = (unsigned int)__ballot(f);

    long rd0 = (long)sdst[wave * 32 + r_lane] * HID;
    long rs0 = (long)ssrc[wave * 32 + r_lane] * HID;
    long rd1 = (long)sdst[wave * 32 + 16 + r_lane] * HID;
    long rs1 = (long)ssrc[wave * 32 + 16 + r_lane] * HID;

    const uint4* Wq = (const uint4*)Wsw;   // granule = 8 bf16
    const __bf16* sWb = (const __bf16*)sWq;

#pragma unroll
    for (int half = 0; half < 2; ++half) {
        // stage this half's 32 fragments (W1a: 16, W1b: 16) into LDS
        __syncthreads();   // half 0: redundant-safe; half 1: protect prior reads
#pragma unroll
        for (int it = 0; it < 8; ++it) {
            int i = it * 256 + tid;          // 0..2047
            int m2 = i >> 10;                // 0 = W1a, 1 = W1b
            int rem = i & 1023;
            int frag = rem >> 6;             // ks*4+n
            int g = rem & 63;                // lane granule
            int ks = frag >> 2, n = frag & 3;
            int src_g = (m2 ? 4096 : 2048) + (ks * 8 + half * 4 + n) * 64 + g;
            sWq[i] = Wq[src_g];
        }
        __syncthreads();

        f32x4 acc[2][4] = {};
#pragma unroll
        for (int ks = 0; ks < 4; ++ks) {
            int kb = ks * 32 + quad * 8;
            bf16x8 ad0 = *(const bf16x8*)(h + rd0 + kb);
            bf16x8 as0 = *(const bf16x8*)(h + rs0 + kb);
            bf16x8 ad1 = *(const bf16x8*)(h + rd1 + kb);
            bf16x8 as1 = *(const bf16x8*)(h + rs1 + kb);
#pragma unroll
            for (int n = 0; n < 4; ++n) {
                bf16x8 b_d = *(const bf16x8*)(sWb + ((ks * 4 + n) * 64 + lane) * 8);
                bf16x8 b_s = *(const bf16x8*)(sWb + 8192 + ((ks * 4 + n) * 64 + lane) * 8);
                acc[0][n] = __builtin_amdgcn_mfma_f32_16x16x32_bf16(ad0, b_d, acc[0][n], 0, 0, 0);
                acc[0][n] = __builtin_amdgcn_mfma_f32_16x16x32_bf16(as0, b_s, acc[0][n], 0, 0, 0);
                acc[1][n] = __builtin_amdgcn_mfma_f32_16x16x32_bf16(ad1, b_d, acc[1][n], 0, 0, 0);
                acc[1][n] = __builtin_amdgcn_mfma_f32_16x16x32_bf16(as1, b_s, acc[1][n], 0, 0, 0);
            }
        }

        // bias + relu in-register
#pragma unroll
        for (int n = 0; n < 4; ++n) {
            float bias = b1[(half * 4 + n) * 16 + r_lane];
#pragma unroll
            for (int mt = 0; mt < 2; ++mt)
#pragma unroll
                for (int r = 0; r < 4; ++r) {
                    float v = acc[mt][n][r] + bias;
                    acc[mt][n][r] = v > 0.f ? v : 0.f;
                }
        }

        // segmented reduce over this wave's 32 rows (wave-uniform loop)
        unsigned int rem = bmask & ~1u;
        int a = 0;
        for (;;) {
            int bnd = rem ? (__ffs(rem) - 1) : 32;
            bool p[2][4];
#pragma unroll
            for (int mt = 0; mt < 2; ++mt)
#pragma unroll
                for (int r = 0; r < 4; ++r) {
                    int row = mt * 16 + quad * 4 + r;
                    p[mt][r] = (row >= a) && (row < bnd);
                }
            long dbase = (long)sdst[wave * 32 + a] * HID;
#pragma unroll
            for (int n = 0; n < 4; ++n) {
                float s = 0.f;
#pragma unroll
                for (int mt = 0; mt < 2; ++mt)
#pragma unroll
                    for (int r = 0; r < 4; ++r)
                        s += p[mt][r] ? acc[mt][n][r] : 0.f;
                s += __shfl_xor(s, 16);
                s += __shfl_xor(s, 32);
                if (lane < 16)
                    atomicAdd(&Tagg[dbase + (half * 4 + n) * 16 + r_lane], s);
            }
            if (bnd >= 32) break;
            a = bnd;
            rem &= rem - 1;
        }
    }
}

// ---------------------------------------------------------------------------
// Node finish: h2 = relu(Tagg @ W2 + deg*b2); out = h2 @ Wc + bc (fused).
// ---------------------------------------------------------------------------
__global__ __launch_bounds__(256) void node_kernel(
    const float* __restrict__ Tagg, const __bf16* __restrict__ Wsw,
    const int* __restrict__ hist, const float* __restrict__ b2,
    const float* __restrict__ Wc, const float* __restrict__ bc,
    float* __restrict__ out)
{
    __shared__ __bf16 At[128][136];
    int tid = threadIdx.x;
    int wave = tid >> 6, lane = tid & 63;
    int m0 = blockIdx.x * 128;

    for (int i = tid; i < 128 * 32; i += 256) {
        int r = i >> 5, c = i & 31;
        int row = m0 + r;
        float4 v = make_float4(0.f, 0.f, 0.f, 0.f);
        if (row < N_NODES) v = *(const float4*)(Tagg + (long)row * HID + c * 4);
        __bf16* dst = &At[r][c * 4];
        dst[0] = (__bf16)v.x; dst[1] = (__bf16)v.y;
        dst[2] = (__bf16)v.z; dst[3] = (__bf16)v.w;
    }
    __syncthreads();

    const __bf16* W2f = Wsw + 49152;
    f32x4 acc[2][8] = {};
    int r_lane = lane & 15, quad = lane >> 4;
#pragma unroll
    for (int ks = 0; ks < 4; ++ks) {
        int kb = ks * 32 + quad * 8;
        bf16x8 a0 = *(const bf16x8*)(&At[wave * 32 + r_lane][kb]);
        bf16x8 a1 = *(const bf16x8*)(&At[wave * 32 + 16 + r_lane][kb]);
#pragma unroll
        for (int n = 0; n < 8; ++n) {
            bf16x8 b = *(const bf16x8*)(W2f + ((ks * 8 + n) * 64 + lane) * 8);
            acc[0][n] = __builtin_amdgcn_mfma_f32_16x16x32_bf16(a0, b, acc[0][n], 0, 0, 0);
            acc[1][n] = __builtin_amdgcn_mfma_f32_16x16x32_bf16(a1, b, acc[1][n], 0, 0, 0);
        }
    }

#pragma unroll
    for (int mt = 0; mt < 2; ++mt) {
#pragma unroll
        for (int r = 0; r < 4; ++r) {
            int row = m0 + wave * 32 + mt * 16 + quad * 4 + r;
            float deg = (row < N_NODES) ? (float)hist[row] : 0.f;
            float s0 = 0.f, s1 = 0.f;
#pragma unroll
            for (int n = 0; n < 8; ++n) {
                int col = n * 16 + r_lane;
                float v = acc[mt][n][r] + deg * b2[col];
                v = v > 0.f ? v : 0.f;
                s0 += v * Wc[col * 2 + 0];
                s1 += v * Wc[col * 2 + 1];
            }
#pragma unroll
            for (int off = 1; off < 16; off <<= 1) {
                s0 += __shfl_xor(s0, off);
                s1 += __shfl_xor(s1, off);
            }
            if (r_lane == 0 && row < N_NODES) {
                out[(long)row * 2 + 0] = s0 + bc[0];
                out[(long)row * 2 + 1] = s1 + bc[1];
            }
        }
    }
}

extern "C" void kernel_launch(void* const* d_in, const int* in_sizes, int n_in,
                              void* d_out, int out_size, void* d_ws, size_t ws_size,
                              hipStream_t stream) {
    const float* x    = (const float*)d_in[0];
    const int* eidx   = (const int*)d_in[1];
    const float* W_in = (const float*)d_in[2];
    const float* b_in = (const float*)d_in[3];
    const float* W1   = (const float*)d_in[4];
    const float* b1   = (const float*)d_in[5];
    const float* W2   = (const float*)d_in[6];
    const float* b2   = (const float*)d_in[7];
    const float* Wc   = (const float*)d_in[8];
    const float* bc   = (const float*)d_in[9];
    float* out = (float*)d_out;

    char* ws = (char*)d_ws;
    __bf16* h   = (__bf16*)(ws + 0);              // 12,800,000
    float* Tagg = (float*)(ws + 12800000);        // 25,600,000
    int2* es    = (int2*)(ws + 38400000);         //  6,400,000
    int* hist   = (int*)(ws + 44800000);          //    200,000
    int* loc    = (int*)(ws + 45000000);          //    200,000
    int* cursor = (int*)(ws + 45200000);          //    200,000
    int* bsum   = (int*)(ws + 45400000);          //      1,024
    __bf16* Wsw = (__bf16*)(ws + 45401024);       //    131,072

    hipMemsetAsync(hist, 0, (size_t)N_NODES * sizeof(int), stream);
    hipMemsetAsync(Tagg, 0, (size_t)N_NODES * HID * sizeof(float), stream);

    prep_kernel<<<256 + (N_EDGES + 255) / 256, 256, 0, stream>>>(W_in, W1, W2, Wsw, eidx, hist);
    proj_kernel<<<(N_NODES + 127) / 128, 256, 0, stream>>>(x, Wsw, b_in, h);
    scan_a<<<SCAN_B, 256, 0, stream>>>(hist, loc, bsum);
    scan_b<<<1, 256, 0, stream>>>(bsum);
    scan_c<<<SCAN_B, 256, 0, stream>>>(loc, bsum, cursor);
    permute_kernel<<<(N_EDGES + 255) / 256, 256, 0, stream>>>(eidx, cursor, es);
    edge1_kernel<<<N_EDGES / 128, 256, 0, stream>>>(h, es, Wsw, b1, Tagg);
    node_kernel<<<(N_NODES + 127) / 128, 256, 0, stream>>>(Tagg, Wsw, hist, b2, Wc, bc, out);
}

// Round 8
// 281.776 us; speedup vs baseline: 1.5681x; 1.1412x over previous
//
#include <hip/hip_runtime.h>
#include <hip/hip_bf16.h>

#define N_NODES 50000
#define N_EDGES 800000
#define HID 128
#define SCAN_B 196      // ceil(50000/256)

typedef __bf16 bf16x8 __attribute__((ext_vector_type(8)));
typedef float f32x4 __attribute__((ext_vector_type(4)));

// ---------------------------------------------------------------------------
// prep: blocks [0,256) repack weights into MFMA-B-fragment-major bf16;
//       blocks [256,...) histogram edge dst.
// Wsw[m][((kstep*8+ntile)*64+lane)*8+j] = W_m[kstep*32+(lane>>4)*8+j][ntile*16+(lane&15)]
// m=0: W_in, m=1: W1[:128] (dst half), m=2: W1[128:] (src half), m=3: W2
// ---------------------------------------------------------------------------
__global__ __launch_bounds__(256) void prep_kernel(
    const float* __restrict__ Win, const float* __restrict__ W1,
    const float* __restrict__ W2, __bf16* __restrict__ Wsw,
    const int* __restrict__ eidx, int* __restrict__ hist)
{
    int b = blockIdx.x;
    int tid = threadIdx.x;
    if (b < 256) {
        int id = b * 256 + tid;   // 0..65535
        int m     = id >> 14;
        int rem   = id & 16383;
        int j     = rem & 7;
        int lane  = (rem >> 3) & 63;
        int ntile = (rem >> 9) & 7;
        int kstep = rem >> 12;
        int k = kstep * 32 + (lane >> 4) * 8 + j;
        int n = ntile * 16 + (lane & 15);
        float v;
        if (m == 0)      v = Win[k * HID + n];
        else if (m == 1) v = W1[k * HID + n];
        else if (m == 2) v = W1[(k + HID) * HID + n];
        else             v = W2[k * HID + n];
        Wsw[id] = (__bf16)v;
    } else {
        int e = (b - 256) * 256 + tid;
        if (e < N_EDGES) atomicAdd(&hist[eidx[N_EDGES + e]], 1);
    }
}

// ---------------------------------------------------------------------------
// projp: fused input projection + per-node message-precompute.
//   h   = relu(x @ W_in + b_in)        (bf16, kept in LDS only)
//   P1a = h @ W1a + b1                 (f32 out; later aliased as Tagg)
//   P1b = h @ W1b                      (bf16 out)
// All LDS slabs are wave-private after the initial x staging barrier:
// wave w reads/writes only rows [32w, 32w+32) of At.
// ---------------------------------------------------------------------------
__global__ __launch_bounds__(256) void projp_kernel(
    const float* __restrict__ x, const __bf16* __restrict__ Wsw,
    const float* __restrict__ b_in, const float* __restrict__ b1,
    float* __restrict__ P1a, __bf16* __restrict__ P1b)
{
    __shared__ __bf16 At[128][136];
    int tid = threadIdx.x;
    int wave = tid >> 6, lane = tid & 63;
    int r_lane = lane & 15, quad = lane >> 4;
    int m0 = blockIdx.x * 128;

    // stage x tile (f32 -> bf16)
    for (int i = tid; i < 128 * 32; i += 256) {
        int r = i >> 5, c = i & 31;
        int row = m0 + r;
        float4 v = make_float4(0.f, 0.f, 0.f, 0.f);
        if (row < N_NODES) v = *(const float4*)(x + (long)row * HID + c * 4);
        __bf16* dst = &At[r][c * 4];
        dst[0] = (__bf16)v.x; dst[1] = (__bf16)v.y;
        dst[2] = (__bf16)v.z; dst[3] = (__bf16)v.w;
    }
    __syncthreads();

    // ---- stage 1: h = relu(x @ W_in + b_in), written back in place ----
    {
        f32x4 acc[2][8] = {};
#pragma unroll
        for (int ks = 0; ks < 4; ++ks) {
            int kb = ks * 32 + quad * 8;
            bf16x8 a0 = *(const bf16x8*)(&At[wave * 32 + r_lane][kb]);
            bf16x8 a1 = *(const bf16x8*)(&At[wave * 32 + 16 + r_lane][kb]);
#pragma unroll
            for (int n = 0; n < 8; ++n) {
                bf16x8 b = *(const bf16x8*)(Wsw + ((ks * 8 + n) * 64 + lane) * 8);
                acc[0][n] = __builtin_amdgcn_mfma_f32_16x16x32_bf16(a0, b, acc[0][n], 0, 0, 0);
                acc[1][n] = __builtin_amdgcn_mfma_f32_16x16x32_bf16(a1, b, acc[1][n], 0, 0, 0);
            }
        }
#pragma unroll
        for (int n = 0; n < 8; ++n) {
            int col = n * 16 + r_lane;
            float bias = b_in[col];
#pragma unroll
            for (int mt = 0; mt < 2; ++mt) {
                int rb = wave * 32 + mt * 16 + quad * 4;
#pragma unroll
                for (int r = 0; r < 4; ++r) {
                    float v = acc[mt][n][r] + bias;
                    At[rb + r][col] = (__bf16)(v > 0.f ? v : 0.f);
                }
            }
        }
    }
    __syncthreads();   // paranoia; all deps are wave-private

    // ---- stage 2a: P1a = h @ W1a + b1 (f32) ----
    {
        const __bf16* W1a = Wsw + 16384;
        f32x4 acc[2][8] = {};
#pragma unroll
        for (int ks = 0; ks < 4; ++ks) {
            int kb = ks * 32 + quad * 8;
            bf16x8 a0 = *(const bf16x8*)(&At[wave * 32 + r_lane][kb]);
            bf16x8 a1 = *(const bf16x8*)(&At[wave * 32 + 16 + r_lane][kb]);
#pragma unroll
            for (int n = 0; n < 8; ++n) {
                bf16x8 b = *(const bf16x8*)(W1a + ((ks * 8 + n) * 64 + lane) * 8);
                acc[0][n] = __builtin_amdgcn_mfma_f32_16x16x32_bf16(a0, b, acc[0][n], 0, 0, 0);
                acc[1][n] = __builtin_amdgcn_mfma_f32_16x16x32_bf16(a1, b, acc[1][n], 0, 0, 0);
            }
        }
#pragma unroll
        for (int n = 0; n < 8; ++n) {
            int col = n * 16 + r_lane;
            float bias = b1[col];
#pragma unroll
            for (int mt = 0; mt < 2; ++mt) {
                int rbase = m0 + wave * 32 + mt * 16 + quad * 4;
#pragma unroll
                for (int r = 0; r < 4; ++r) {
                    int row = rbase + r;
                    if (row < N_NODES)
                        P1a[(long)row * HID + col] = acc[mt][n][r] + bias;
                }
            }
        }
    }

    // ---- stage 2b: P1b = h @ W1b (bf16) ----
    {
        const __bf16* W1b = Wsw + 32768;
        f32x4 acc[2][8] = {};
#pragma unroll
        for (int ks = 0; ks < 4; ++ks) {
            int kb = ks * 32 + quad * 8;
            bf16x8 a0 = *(const bf16x8*)(&At[wave * 32 + r_lane][kb]);
            bf16x8 a1 = *(const bf16x8*)(&At[wave * 32 + 16 + r_lane][kb]);
#pragma unroll
            for (int n = 0; n < 8; ++n) {
                bf16x8 b = *(const bf16x8*)(W1b + ((ks * 8 + n) * 64 + lane) * 8);
                acc[0][n] = __builtin_amdgcn_mfma_f32_16x16x32_bf16(a0, b, acc[0][n], 0, 0, 0);
                acc[1][n] = __builtin_amdgcn_mfma_f32_16x16x32_bf16(a1, b, acc[1][n], 0, 0, 0);
            }
        }
#pragma unroll
        for (int n = 0; n < 8; ++n) {
            int col = n * 16 + r_lane;
#pragma unroll
            for (int mt = 0; mt < 2; ++mt) {
                int rbase = m0 + wave * 32 + mt * 16 + quad * 4;
#pragma unroll
                for (int r = 0; r < 4; ++r) {
                    int row = rbase + r;
                    if (row < N_NODES)
                        P1b[(long)row * HID + col] = (__bf16)acc[mt][n][r];
                }
            }
        }
    }
}

// ---------------------------------------------------------------------------
// Parallel scan hierarchy: scan_a (per-block) -> scan_b (block sums) -> scan_c
// ---------------------------------------------------------------------------
__global__ __launch_bounds__(256) void scan_a(
    const int* __restrict__ hist, int* __restrict__ loc, int* __restrict__ bsum)
{
    __shared__ int s[256];
    int t = threadIdx.x;
    int i = blockIdx.x * 256 + t;
    int v = (i < N_NODES) ? hist[i] : 0;
    s[t] = v;
    __syncthreads();
    for (int d = 1; d < 256; d <<= 1) {
        int tv = (t >= d) ? s[t - d] : 0;
        __syncthreads();
        s[t] += tv;
        __syncthreads();
    }
    if (i < N_NODES) loc[i] = s[t] - v;
    if (t == 255) bsum[blockIdx.x] = s[255];
}

__global__ __launch_bounds__(256) void scan_b(int* __restrict__ bsum)
{
    __shared__ int s[256];
    int t = threadIdx.x;
    int v = (t < SCAN_B) ? bsum[t] : 0;
    s[t] = v;
    __syncthreads();
    for (int d = 1; d < 256; d <<= 1) {
        int tv = (t >= d) ? s[t - d] : 0;
        __syncthreads();
        s[t] += tv;
        __syncthreads();
    }
    if (t < SCAN_B) bsum[t] = s[t] - v;   // exclusive
}

__global__ __launch_bounds__(256) void scan_c(
    const int* __restrict__ loc, const int* __restrict__ bsum,
    int* __restrict__ offs, int* __restrict__ cursor)
{
    int i = blockIdx.x * 256 + threadIdx.x;
    if (i < N_NODES) {
        int o = loc[i] + bsum[blockIdx.x];
        offs[i] = o;
        cursor[i] = o;
    }
}

// permute: scatter src indices into dst-sorted order (src only; dst implied by CSR)
__global__ __launch_bounds__(256) void permute_kernel(
    const int* __restrict__ eidx, int* __restrict__ cursor, int* __restrict__ srt)
{
    int e = blockIdx.x * 256 + threadIdx.x;
    if (e < N_EDGES) {
        int d = eidx[N_EDGES + e];
        int pos = atomicAdd(&cursor[d], 1);
        srt[pos] = eidx[e];
    }
}

// ---------------------------------------------------------------------------
// agg: node-parallel CSR aggregation — NO atomics, no edge MFMA.
//   Tagg[d] = sum_{e in edges(d)} relu(P1a[d] + P1b[src_e])
// 32-lane team per node, 4 cols/lane. Tagg aliases P1a: each team reads its
// P1a row before overwriting it, rows are team-private.
// ---------------------------------------------------------------------------
__global__ __launch_bounds__(256) void agg_kernel(
    const float* __restrict__ P1a, const __bf16* __restrict__ P1b,
    const int* __restrict__ srt, const int* __restrict__ offs,
    const int* __restrict__ hist, float* __restrict__ Tagg)
{
    int tid = threadIdx.x;
    int team = tid >> 5;            // 0..7
    int tl = tid & 31;              // lane in team -> cols [4tl, 4tl+4)
    int node = blockIdx.x * 8 + team;
    if (node >= N_NODES) return;

    int beg = offs[node];
    int deg = hist[node];

    float4 pa = *(const float4*)(P1a + (long)node * HID + tl * 4);
    float4 run = make_float4(0.f, 0.f, 0.f, 0.f);

    int src = (deg > 0) ? srt[beg] : 0;
    for (int j = 0; j < deg; ++j) {
        int nsrc = (j + 1 < deg) ? srt[beg + j + 1] : 0;   // prefetch next index
        ushort4 u = *(const ushort4*)(P1b + (long)src * HID + tl * 4);
        float t0 = pa.x + __uint_as_float((unsigned)u.x << 16);
        float t1 = pa.y + __uint_as_float((unsigned)u.y << 16);
        float t2 = pa.z + __uint_as_float((unsigned)u.z << 16);
        float t3 = pa.w + __uint_as_float((unsigned)u.w << 16);
        run.x += t0 > 0.f ? t0 : 0.f;
        run.y += t1 > 0.f ? t1 : 0.f;
        run.z += t2 > 0.f ? t2 : 0.f;
        run.w += t3 > 0.f ? t3 : 0.f;
        src = nsrc;
    }
    *(float4*)(Tagg + (long)node * HID + tl * 4) = run;
}

// ---------------------------------------------------------------------------
// Node finish: h2 = relu(Tagg @ W2 + deg*b2); out = h2 @ Wc + bc (fused).
// ---------------------------------------------------------------------------
__global__ __launch_bounds__(256) void node_kernel(
    const float* __restrict__ Tagg, const __bf16* __restrict__ Wsw,
    const int* __restrict__ hist, const float* __restrict__ b2,
    const float* __restrict__ Wc, const float* __restrict__ bc,
    float* __restrict__ out)
{
    __shared__ __bf16 At[128][136];
    int tid = threadIdx.x;
    int wave = tid >> 6, lane = tid & 63;
    int m0 = blockIdx.x * 128;

    for (int i = tid; i < 128 * 32; i += 256) {
        int r = i >> 5, c = i & 31;
        int row = m0 + r;
        float4 v = make_float4(0.f, 0.f, 0.f, 0.f);
        if (row < N_NODES) v = *(const float4*)(Tagg + (long)row * HID + c * 4);
        __bf16* dst = &At[r][c * 4];
        dst[0] = (__bf16)v.x; dst[1] = (__bf16)v.y;
        dst[2] = (__bf16)v.z; dst[3] = (__bf16)v.w;
    }
    __syncthreads();

    const __bf16* W2f = Wsw + 49152;
    f32x4 acc[2][8] = {};
    int r_lane = lane & 15, quad = lane >> 4;
#pragma unroll
    for (int ks = 0; ks < 4; ++ks) {
        int kb = ks * 32 + quad * 8;
        bf16x8 a0 = *(const bf16x8*)(&At[wave * 32 + r_lane][kb]);
        bf16x8 a1 = *(const bf16x8*)(&At[wave * 32 + 16 + r_lane][kb]);
#pragma unroll
        for (int n = 0; n < 8; ++n) {
            bf16x8 b = *(const bf16x8*)(W2f + ((ks * 8 + n) * 64 + lane) * 8);
            acc[0][n] = __builtin_amdgcn_mfma_f32_16x16x32_bf16(a0, b, acc[0][n], 0, 0, 0);
            acc[1][n] = __builtin_amdgcn_mfma_f32_16x16x32_bf16(a1, b, acc[1][n], 0, 0, 0);
        }
    }

#pragma unroll
    for (int mt = 0; mt < 2; ++mt) {
#pragma unroll
        for (int r = 0; r < 4; ++r) {
            int row = m0 + wave * 32 + mt * 16 + quad * 4 + r;
            float deg = (row < N_NODES) ? (float)hist[row] : 0.f;
            float s0 = 0.f, s1 = 0.f;
#pragma unroll
            for (int n = 0; n < 8; ++n) {
                int col = n * 16 + r_lane;
                float v = acc[mt][n][r] + deg * b2[col];
                v = v > 0.f ? v : 0.f;
                s0 += v * Wc[col * 2 + 0];
                s1 += v * Wc[col * 2 + 1];
            }
#pragma unroll
            for (int off = 1; off < 16; off <<= 1) {
                s0 += __shfl_xor(s0, off);
                s1 += __shfl_xor(s1, off);
            }
            if (r_lane == 0 && row < N_NODES) {
                out[(long)row * 2 + 0] = s0 + bc[0];
                out[(long)row * 2 + 1] = s1 + bc[1];
            }
        }
    }
}

extern "C" void kernel_launch(void* const* d_in, const int* in_sizes, int n_in,
                              void* d_out, int out_size, void* d_ws, size_t ws_size,
                              hipStream_t stream) {
    const float* x    = (const float*)d_in[0];
    const int* eidx   = (const int*)d_in[1];
    const float* W_in = (const float*)d_in[2];
    const float* b_in = (const float*)d_in[3];
    const float* W1   = (const float*)d_in[4];
    const float* b1   = (const float*)d_in[5];
    const float* W2   = (const float*)d_in[6];
    const float* b2   = (const float*)d_in[7];
    const float* Wc   = (const float*)d_in[8];
    const float* bc   = (const float*)d_in[9];
    float* out = (float*)d_out;

    char* ws = (char*)d_ws;
    float*  P1a  = (float*)(ws + 0);              // 25,600,000 (aliased as Tagg)
    float*  Tagg = P1a;
    __bf16* P1b  = (__bf16*)(ws + 25600000);      // 12,800,000
    int* srt     = (int*)(ws + 38400000);         //  3,200,000
    int* hist    = (int*)(ws + 41600000);         //    200,000
    int* loc     = (int*)(ws + 41800000);         //    200,000
    int* offs    = (int*)(ws + 42000000);         //    200,000
    int* cursor  = (int*)(ws + 42200000);         //    200,000
    int* bsum    = (int*)(ws + 42400000);         //      1,024
    __bf16* Wsw  = (__bf16*)(ws + 42401024);      //    131,072

    hipMemsetAsync(hist, 0, (size_t)N_NODES * sizeof(int), stream);

    prep_kernel<<<256 + (N_EDGES + 255) / 256, 256, 0, stream>>>(W_in, W1, W2, Wsw, eidx, hist);
    projp_kernel<<<(N_NODES + 127) / 128, 256, 0, stream>>>(x, Wsw, b_in, b1, P1a, P1b);
    scan_a<<<SCAN_B, 256, 0, stream>>>(hist, loc, bsum);
    scan_b<<<1, 256, 0, stream>>>(bsum);
    scan_c<<<SCAN_B, 256, 0, stream>>>(loc, bsum, offs, cursor);
    permute_kernel<<<(N_EDGES + 255) / 256, 256, 0, stream>>>(eidx, cursor, srt);
    agg_kernel<<<(N_NODES + 7) / 8, 256, 0, stream>>>(P1a, P1b, srt, offs, hist, Tagg);
    node_kernel<<<(N_NODES + 127) / 128, 256, 0, stream>>>(Tagg, Wsw, hist, b2, Wc, bc, out);
}

// Round 9
// 276.031 us; speedup vs baseline: 1.6007x; 1.0208x over previous
//
#include <hip/hip_runtime.h>
#include <hip/hip_bf16.h>

#define N_NODES 50000
#define N_EDGES 800000
#define HID 128
#define SCAN_B 196      // ceil(50000/256)

typedef __bf16 bf16x8 __attribute__((ext_vector_type(8)));
typedef float f32x4 __attribute__((ext_vector_type(4)));

// ---------------------------------------------------------------------------
// prep: blocks [0,256) repack weights into MFMA-B-fragment-major bf16;
//       blocks [256,...) histogram edge dst.
// Wsw[m][((kstep*8+ntile)*64+lane)*8+j] = W_m[kstep*32+(lane>>4)*8+j][ntile*16+(lane&15)]
// m=0: W_in, m=1: W1[:128] (dst half), m=2: W1[128:] (src half), m=3: W2
// ---------------------------------------------------------------------------
__global__ __launch_bounds__(256) void prep_kernel(
    const float* __restrict__ Win, const float* __restrict__ W1,
    const float* __restrict__ W2, __bf16* __restrict__ Wsw,
    const int* __restrict__ eidx, int* __restrict__ hist)
{
    int b = blockIdx.x;
    int tid = threadIdx.x;
    if (b < 256) {
        int id = b * 256 + tid;   // 0..65535
        int m     = id >> 14;
        int rem   = id & 16383;
        int j     = rem & 7;
        int lane  = (rem >> 3) & 63;
        int ntile = (rem >> 9) & 7;
        int kstep = rem >> 12;
        int k = kstep * 32 + (lane >> 4) * 8 + j;
        int n = ntile * 16 + (lane & 15);
        float v;
        if (m == 0)      v = Win[k * HID + n];
        else if (m == 1) v = W1[k * HID + n];
        else if (m == 2) v = W1[(k + HID) * HID + n];
        else             v = W2[k * HID + n];
        Wsw[id] = (__bf16)v;
    } else {
        int e = (b - 256) * 256 + tid;
        if (e < N_EDGES) atomicAdd(&hist[eidx[N_EDGES + e]], 1);
    }
}

// ---------------------------------------------------------------------------
// projp: fused input projection + per-node message-precompute.
//   h   = relu(x @ W_in + b_in)        (bf16, kept in LDS only)
//   P1a = h @ W1a + b1                 (f32 out)
//   P1b = h @ W1b                      (bf16 out)
// ---------------------------------------------------------------------------
__global__ __launch_bounds__(256) void projp_kernel(
    const float* __restrict__ x, const __bf16* __restrict__ Wsw,
    const float* __restrict__ b_in, const float* __restrict__ b1,
    float* __restrict__ P1a, __bf16* __restrict__ P1b)
{
    __shared__ __bf16 At[128][136];
    int tid = threadIdx.x;
    int wave = tid >> 6, lane = tid & 63;
    int r_lane = lane & 15, quad = lane >> 4;
    int m0 = blockIdx.x * 128;

    // stage x tile (f32 -> bf16)
    for (int i = tid; i < 128 * 32; i += 256) {
        int r = i >> 5, c = i & 31;
        int row = m0 + r;
        float4 v = make_float4(0.f, 0.f, 0.f, 0.f);
        if (row < N_NODES) v = *(const float4*)(x + (long)row * HID + c * 4);
        __bf16* dst = &At[r][c * 4];
        dst[0] = (__bf16)v.x; dst[1] = (__bf16)v.y;
        dst[2] = (__bf16)v.z; dst[3] = (__bf16)v.w;
    }
    __syncthreads();

    // ---- stage 1: h = relu(x @ W_in + b_in), written back in place ----
    {
        f32x4 acc[2][8] = {};
#pragma unroll
        for (int ks = 0; ks < 4; ++ks) {
            int kb = ks * 32 + quad * 8;
            bf16x8 a0 = *(const bf16x8*)(&At[wave * 32 + r_lane][kb]);
            bf16x8 a1 = *(const bf16x8*)(&At[wave * 32 + 16 + r_lane][kb]);
#pragma unroll
            for (int n = 0; n < 8; ++n) {
                bf16x8 b = *(const bf16x8*)(Wsw + ((ks * 8 + n) * 64 + lane) * 8);
                acc[0][n] = __builtin_amdgcn_mfma_f32_16x16x32_bf16(a0, b, acc[0][n], 0, 0, 0);
                acc[1][n] = __builtin_amdgcn_mfma_f32_16x16x32_bf16(a1, b, acc[1][n], 0, 0, 0);
            }
        }
#pragma unroll
        for (int n = 0; n < 8; ++n) {
            int col = n * 16 + r_lane;
            float bias = b_in[col];
#pragma unroll
            for (int mt = 0; mt < 2; ++mt) {
                int rb = wave * 32 + mt * 16 + quad * 4;
#pragma unroll
                for (int r = 0; r < 4; ++r) {
                    float v = acc[mt][n][r] + bias;
                    At[rb + r][col] = (__bf16)(v > 0.f ? v : 0.f);
                }
            }
        }
    }
    __syncthreads();

    // ---- stage 2a: P1a = h @ W1a + b1 (f32) ----
    {
        const __bf16* W1a = Wsw + 16384;
        f32x4 acc[2][8] = {};
#pragma unroll
        for (int ks = 0; ks < 4; ++ks) {
            int kb = ks * 32 + quad * 8;
            bf16x8 a0 = *(const bf16x8*)(&At[wave * 32 + r_lane][kb]);
            bf16x8 a1 = *(const bf16x8*)(&At[wave * 32 + 16 + r_lane][kb]);
#pragma unroll
            for (int n = 0; n < 8; ++n) {
                bf16x8 b = *(const bf16x8*)(W1a + ((ks * 8 + n) * 64 + lane) * 8);
                acc[0][n] = __builtin_amdgcn_mfma_f32_16x16x32_bf16(a0, b, acc[0][n], 0, 0, 0);
                acc[1][n] = __builtin_amdgcn_mfma_f32_16x16x32_bf16(a1, b, acc[1][n], 0, 0, 0);
            }
        }
#pragma unroll
        for (int n = 0; n < 8; ++n) {
            int col = n * 16 + r_lane;
            float bias = b1[col];
#pragma unroll
            for (int mt = 0; mt < 2; ++mt) {
                int rbase = m0 + wave * 32 + mt * 16 + quad * 4;
#pragma unroll
                for (int r = 0; r < 4; ++r) {
                    int row = rbase + r;
                    if (row < N_NODES)
                        P1a[(long)row * HID + col] = acc[mt][n][r] + bias;
                }
            }
        }
    }

    // ---- stage 2b: P1b = h @ W1b (bf16) ----
    {
        const __bf16* W1b = Wsw + 32768;
        f32x4 acc[2][8] = {};
#pragma unroll
        for (int ks = 0; ks < 4; ++ks) {
            int kb = ks * 32 + quad * 8;
            bf16x8 a0 = *(const bf16x8*)(&At[wave * 32 + r_lane][kb]);
            bf16x8 a1 = *(const bf16x8*)(&At[wave * 32 + 16 + r_lane][kb]);
#pragma unroll
            for (int n = 0; n < 8; ++n) {
                bf16x8 b = *(const bf16x8*)(W1b + ((ks * 8 + n) * 64 + lane) * 8);
                acc[0][n] = __builtin_amdgcn_mfma_f32_16x16x32_bf16(a0, b, acc[0][n], 0, 0, 0);
                acc[1][n] = __builtin_amdgcn_mfma_f32_16x16x32_bf16(a1, b, acc[1][n], 0, 0, 0);
            }
        }
#pragma unroll
        for (int n = 0; n < 8; ++n) {
            int col = n * 16 + r_lane;
#pragma unroll
            for (int mt = 0; mt < 2; ++mt) {
                int rbase = m0 + wave * 32 + mt * 16 + quad * 4;
#pragma unroll
                for (int r = 0; r < 4; ++r) {
                    int row = rbase + r;
                    if (row < N_NODES)
                        P1b[(long)row * HID + col] = (__bf16)acc[mt][n][r];
                }
            }
        }
    }
}

// ---------------------------------------------------------------------------
// scan_a: per-block exclusive scan of hist -> loc, block totals -> bsum
// ---------------------------------------------------------------------------
__global__ __launch_bounds__(256) void scan_a(
    const int* __restrict__ hist, int* __restrict__ loc, int* __restrict__ bsum)
{
    __shared__ int s[256];
    int t = threadIdx.x;
    int i = blockIdx.x * 256 + t;
    int v = (i < N_NODES) ? hist[i] : 0;
    s[t] = v;
    __syncthreads();
    for (int d = 1; d < 256; d <<= 1) {
        int tv = (t >= d) ? s[t - d] : 0;
        __syncthreads();
        s[t] += tv;
        __syncthreads();
    }
    if (i < N_NODES) loc[i] = s[t] - v;
    if (t == 255) bsum[blockIdx.x] = s[255];
}

// scan_c: add inter-block prefix (serial inline, proven R4 pattern)
__global__ __launch_bounds__(256) void scan_c(
    const int* __restrict__ loc, const int* __restrict__ bsum,
    int* __restrict__ offs, int* __restrict__ cursor)
{
    __shared__ int pre;
    if (threadIdx.x == 0) {
        int s = 0;
        for (int b = 0; b < (int)blockIdx.x; ++b) s += bsum[b];
        pre = s;
    }
    __syncthreads();
    int i = blockIdx.x * 256 + threadIdx.x;
    if (i < N_NODES) {
        int o = loc[i] + pre;
        offs[i] = o;
        cursor[i] = o;
    }
}

// permute: scatter src indices into dst-sorted order (dst implied by CSR)
__global__ __launch_bounds__(256) void permute_kernel(
    const int* __restrict__ eidx, int* __restrict__ cursor, int* __restrict__ srt)
{
    int e = blockIdx.x * 256 + threadIdx.x;
    if (e < N_EDGES) {
        int d = eidx[N_EDGES + e];
        int pos = atomicAdd(&cursor[d], 1);
        srt[pos] = eidx[e];
    }
}

// ---------------------------------------------------------------------------
// 8 relu-accumulates of one P1b row (8 bf16 in uint4) against P1a (f32x8)
// ---------------------------------------------------------------------------
__device__ inline void acc8(float4& rA, float4& rB,
                            const float4 paA, const float4 paB, uint4 q)
{
    float t;
    t = paA.x + __uint_as_float(q.x << 16);         rA.x += t > 0.f ? t : 0.f;
    t = paA.y + __uint_as_float(q.x & 0xffff0000u); rA.y += t > 0.f ? t : 0.f;
    t = paA.z + __uint_as_float(q.y << 16);         rA.z += t > 0.f ? t : 0.f;
    t = paA.w + __uint_as_float(q.y & 0xffff0000u); rA.w += t > 0.f ? t : 0.f;
    t = paB.x + __uint_as_float(q.z << 16);         rB.x += t > 0.f ? t : 0.f;
    t = paB.y + __uint_as_float(q.z & 0xffff0000u); rB.y += t > 0.f ? t : 0.f;
    t = paB.z + __uint_as_float(q.w << 16);         rB.z += t > 0.f ? t : 0.f;
    t = paB.w + __uint_as_float(q.w & 0xffff0000u); rB.w += t > 0.f ? t : 0.f;
}

// ---------------------------------------------------------------------------
// aggnode: fused CSR aggregation + node finish. Block = 128 nodes.
// Phase 1: 16 teams x 16 lanes; team aggregates 8 rows directly into LDS At
//          (bf16), edge loop unrolled x4 for 4 gathers in flight per lane.
//   At[r] = (bf16) sum_e relu(P1a[node] + P1b[src_e])
// Phase 2: h2 = relu(At @ W2 + deg*b2); out = h2 @ Wc + bc   (proven MFMA)
// ---------------------------------------------------------------------------
__global__ __launch_bounds__(256) void aggnode_kernel(
    const float* __restrict__ P1a, const __bf16* __restrict__ P1b,
    const int* __restrict__ srt, const int* __restrict__ offs,
    const int* __restrict__ hist, const __bf16* __restrict__ Wsw,
    const float* __restrict__ b2, const float* __restrict__ Wc,
    const float* __restrict__ bc, float* __restrict__ out)
{
    __shared__ __bf16 At[128][136];
    int tid = threadIdx.x;
    int m0 = blockIdx.x * 128;

    // ---- phase 1: aggregate into At ----
    {
        int team = tid >> 4;        // 0..15
        int tl = tid & 15;          // cols [8tl, 8tl+8)
        for (int g = 0; g < 8; ++g) {
            int r = team * 8 + g;
            int node = m0 + r;
            float4 rA = make_float4(0.f, 0.f, 0.f, 0.f);
            float4 rB = make_float4(0.f, 0.f, 0.f, 0.f);
            if (node < N_NODES) {
                int beg = offs[node];
                int deg = hist[node];
                const float* par = P1a + (long)node * HID + tl * 8;
                float4 paA = *(const float4*)par;
                float4 paB = *(const float4*)(par + 4);
                int j = 0;
                for (; j + 4 <= deg; j += 4) {
                    int s0 = srt[beg + j];
                    int s1 = srt[beg + j + 1];
                    int s2 = srt[beg + j + 2];
                    int s3 = srt[beg + j + 3];
                    uint4 q0 = *(const uint4*)(P1b + (long)s0 * HID + tl * 8);
                    uint4 q1 = *(const uint4*)(P1b + (long)s1 * HID + tl * 8);
                    uint4 q2 = *(const uint4*)(P1b + (long)s2 * HID + tl * 8);
                    uint4 q3 = *(const uint4*)(P1b + (long)s3 * HID + tl * 8);
                    acc8(rA, rB, paA, paB, q0);
                    acc8(rA, rB, paA, paB, q1);
                    acc8(rA, rB, paA, paB, q2);
                    acc8(rA, rB, paA, paB, q3);
                }
                for (; j < deg; ++j) {
                    int s = srt[beg + j];
                    uint4 q = *(const uint4*)(P1b + (long)s * HID + tl * 8);
                    acc8(rA, rB, paA, paB, q);
                }
            }
            __bf16 vv[8];
            vv[0] = (__bf16)rA.x; vv[1] = (__bf16)rA.y;
            vv[2] = (__bf16)rA.z; vv[3] = (__bf16)rA.w;
            vv[4] = (__bf16)rB.x; vv[5] = (__bf16)rB.y;
            vv[6] = (__bf16)rB.z; vv[7] = (__bf16)rB.w;
            *(uint4*)(&At[r][tl * 8]) = *(uint4*)vv;
        }
    }
    __syncthreads();

    // ---- phase 2: node GEMM (proven) ----
    int wave = tid >> 6, lane = tid & 63;
    int r_lane = lane & 15, quad = lane >> 4;
    const __bf16* W2f = Wsw + 49152;
    f32x4 acc[2][8] = {};
#pragma unroll
    for (int ks = 0; ks < 4; ++ks) {
        int kb = ks * 32 + quad * 8;
        bf16x8 a0 = *(const bf16x8*)(&At[wave * 32 + r_lane][kb]);
        bf16x8 a1 = *(const bf16x8*)(&At[wave * 32 + 16 + r_lane][kb]);
#pragma unroll
        for (int n = 0; n < 8; ++n) {
            bf16x8 b = *(const bf16x8*)(W2f + ((ks * 8 + n) * 64 + lane) * 8);
            acc[0][n] = __builtin_amdgcn_mfma_f32_16x16x32_bf16(a0, b, acc[0][n], 0, 0, 0);
            acc[1][n] = __builtin_amdgcn_mfma_f32_16x16x32_bf16(a1, b, acc[1][n], 0, 0, 0);
        }
    }

#pragma unroll
    for (int mt = 0; mt < 2; ++mt) {
#pragma unroll
        for (int r = 0; r < 4; ++r) {
            int row = m0 + wave * 32 + mt * 16 + quad * 4 + r;
            float deg = (row < N_NODES) ? (float)hist[row] : 0.f;
            float s0 = 0.f, s1 = 0.f;
#pragma unroll
            for (int n = 0; n < 8; ++n) {
                int col = n * 16 + r_lane;
                float v = acc[mt][n][r] + deg * b2[col];
                v = v > 0.f ? v : 0.f;
                s0 += v * Wc[col * 2 + 0];
                s1 += v * Wc[col * 2 + 1];
            }
#pragma unroll
            for (int off = 1; off < 16; off <<= 1) {
                s0 += __shfl_xor(s0, off);
                s1 += __shfl_xor(s1, off);
            }
            if (r_lane == 0 && row < N_NODES) {
                out[(long)row * 2 + 0] = s0 + bc[0];
                out[(long)row * 2 + 1] = s1 + bc[1];
            }
        }
    }
}

extern "C" void kernel_launch(void* const* d_in, const int* in_sizes, int n_in,
                              void* d_out, int out_size, void* d_ws, size_t ws_size,
                              hipStream_t stream) {
    const float* x    = (const float*)d_in[0];
    const int* eidx   = (const int*)d_in[1];
    const float* W_in = (const float*)d_in[2];
    const float* b_in = (const float*)d_in[3];
    const float* W1   = (const float*)d_in[4];
    const float* b1   = (const float*)d_in[5];
    const float* W2   = (const float*)d_in[6];
    const float* b2   = (const float*)d_in[7];
    const float* Wc   = (const float*)d_in[8];
    const float* bc   = (const float*)d_in[9];
    float* out = (float*)d_out;

    char* ws = (char*)d_ws;
    float*  P1a  = (float*)(ws + 0);              // 25,600,000
    __bf16* P1b  = (__bf16*)(ws + 25600000);      // 12,800,000
    int* srt     = (int*)(ws + 38400000);         //  3,200,000
    int* hist    = (int*)(ws + 41600000);         //    200,000
    int* loc     = (int*)(ws + 41800000);         //    200,000
    int* offs    = (int*)(ws + 42000000);         //    200,000
    int* cursor  = (int*)(ws + 42200000);         //    200,000
    int* bsum    = (int*)(ws + 42400000);         //      1,024
    __bf16* Wsw  = (__bf16*)(ws + 42401024);      //    131,072

    hipMemsetAsync(hist, 0, (size_t)N_NODES * sizeof(int), stream);

    prep_kernel<<<256 + (N_EDGES + 255) / 256, 256, 0, stream>>>(W_in, W1, W2, Wsw, eidx, hist);
    projp_kernel<<<(N_NODES + 127) / 128, 256, 0, stream>>>(x, Wsw, b_in, b1, P1a, P1b);
    scan_a<<<SCAN_B, 256, 0, stream>>>(hist, loc, bsum);
    scan_c<<<SCAN_B, 256, 0, stream>>>(loc, bsum, offs, cursor);
    permute_kernel<<<(N_EDGES + 255) / 256, 256, 0, stream>>>(eidx, cursor, srt);
    aggnode_kernel<<<(N_NODES + 127) / 128, 256, 0, stream>>>(
        P1a, P1b, srt, offs, hist, Wsw, b2, Wc, bc, out);
}

// Round 10
// 261.842 us; speedup vs baseline: 1.6875x; 1.0542x over previous
//
#include <hip/hip_runtime.h>
#include <hip/hip_bf16.h>

#define N_NODES 50000
#define N_EDGES 800000
#define HID 128
#define SCAN_B 196      // ceil(50000/256)

typedef __bf16 bf16x8 __attribute__((ext_vector_type(8)));
typedef float f32x4 __attribute__((ext_vector_type(4)));

// ---------------------------------------------------------------------------
// prep: blocks [0,256) repack weights into MFMA-B-fragment-major bf16;
//       blocks [256,...) histogram edge dst.
// Wsw[m][((kstep*8+ntile)*64+lane)*8+j] = W_m[kstep*32+(lane>>4)*8+j][ntile*16+(lane&15)]
// m=0: W_in, m=1: W1[:128] (dst half), m=2: W1[128:] (src half), m=3: W2
// ---------------------------------------------------------------------------
__global__ __launch_bounds__(256) void prep_kernel(
    const float* __restrict__ Win, const float* __restrict__ W1,
    const float* __restrict__ W2, __bf16* __restrict__ Wsw,
    const int* __restrict__ eidx, int* __restrict__ hist)
{
    int b = blockIdx.x;
    int tid = threadIdx.x;
    if (b < 256) {
        int id = b * 256 + tid;   // 0..65535
        int m     = id >> 14;
        int rem   = id & 16383;
        int j     = rem & 7;
        int lane  = (rem >> 3) & 63;
        int ntile = (rem >> 9) & 7;
        int kstep = rem >> 12;
        int k = kstep * 32 + (lane >> 4) * 8 + j;
        int n = ntile * 16 + (lane & 15);
        float v;
        if (m == 0)      v = Win[k * HID + n];
        else if (m == 1) v = W1[k * HID + n];
        else if (m == 2) v = W1[(k + HID) * HID + n];
        else             v = W2[k * HID + n];
        Wsw[id] = (__bf16)v;
    } else {
        int e = (b - 256) * 256 + tid;
        if (e < N_EDGES) atomicAdd(&hist[eidx[N_EDGES + e]], 1);
    }
}

// ---------------------------------------------------------------------------
// projp: fused input projection + per-node message-precompute.
//   h   = relu(x @ W_in + b_in)        (bf16, kept in LDS only)
//   P1a = h @ W1a + b1                 (f32 out)
//   P1b = h @ W1b                      (bf16 out)
// ---------------------------------------------------------------------------
__global__ __launch_bounds__(256) void projp_kernel(
    const float* __restrict__ x, const __bf16* __restrict__ Wsw,
    const float* __restrict__ b_in, const float* __restrict__ b1,
    float* __restrict__ P1a, __bf16* __restrict__ P1b)
{
    __shared__ __bf16 At[128][136];
    int tid = threadIdx.x;
    int wave = tid >> 6, lane = tid & 63;
    int r_lane = lane & 15, quad = lane >> 4;
    int m0 = blockIdx.x * 128;

    // stage x tile (f32 -> bf16)
    for (int i = tid; i < 128 * 32; i += 256) {
        int r = i >> 5, c = i & 31;
        int row = m0 + r;
        float4 v = make_float4(0.f, 0.f, 0.f, 0.f);
        if (row < N_NODES) v = *(const float4*)(x + (long)row * HID + c * 4);
        __bf16* dst = &At[r][c * 4];
        dst[0] = (__bf16)v.x; dst[1] = (__bf16)v.y;
        dst[2] = (__bf16)v.z; dst[3] = (__bf16)v.w;
    }
    __syncthreads();

    // ---- stage 1: h = relu(x @ W_in + b_in), written back in place ----
    {
        f32x4 acc[2][8] = {};
#pragma unroll
        for (int ks = 0; ks < 4; ++ks) {
            int kb = ks * 32 + quad * 8;
            bf16x8 a0 = *(const bf16x8*)(&At[wave * 32 + r_lane][kb]);
            bf16x8 a1 = *(const bf16x8*)(&At[wave * 32 + 16 + r_lane][kb]);
#pragma unroll
            for (int n = 0; n < 8; ++n) {
                bf16x8 b = *(const bf16x8*)(Wsw + ((ks * 8 + n) * 64 + lane) * 8);
                acc[0][n] = __builtin_amdgcn_mfma_f32_16x16x32_bf16(a0, b, acc[0][n], 0, 0, 0);
                acc[1][n] = __builtin_amdgcn_mfma_f32_16x16x32_bf16(a1, b, acc[1][n], 0, 0, 0);
            }
        }
#pragma unroll
        for (int n = 0; n < 8; ++n) {
            int col = n * 16 + r_lane;
            float bias = b_in[col];
#pragma unroll
            for (int mt = 0; mt < 2; ++mt) {
                int rb = wave * 32 + mt * 16 + quad * 4;
#pragma unroll
                for (int r = 0; r < 4; ++r) {
                    float v = acc[mt][n][r] + bias;
                    At[rb + r][col] = (__bf16)(v > 0.f ? v : 0.f);
                }
            }
        }
    }
    __syncthreads();

    // ---- stage 2a: P1a = h @ W1a + b1 (f32) ----
    {
        const __bf16* W1a = Wsw + 16384;
        f32x4 acc[2][8] = {};
#pragma unroll
        for (int ks = 0; ks < 4; ++ks) {
            int kb = ks * 32 + quad * 8;
            bf16x8 a0 = *(const bf16x8*)(&At[wave * 32 + r_lane][kb]);
            bf16x8 a1 = *(const bf16x8*)(&At[wave * 32 + 16 + r_lane][kb]);
#pragma unroll
            for (int n = 0; n < 8; ++n) {
                bf16x8 b = *(const bf16x8*)(W1a + ((ks * 8 + n) * 64 + lane) * 8);
                acc[0][n] = __builtin_amdgcn_mfma_f32_16x16x32_bf16(a0, b, acc[0][n], 0, 0, 0);
                acc[1][n] = __builtin_amdgcn_mfma_f32_16x16x32_bf16(a1, b, acc[1][n], 0, 0, 0);
            }
        }
#pragma unroll
        for (int n = 0; n < 8; ++n) {
            int col = n * 16 + r_lane;
            float bias = b1[col];
#pragma unroll
            for (int mt = 0; mt < 2; ++mt) {
                int rbase = m0 + wave * 32 + mt * 16 + quad * 4;
#pragma unroll
                for (int r = 0; r < 4; ++r) {
                    int row = rbase + r;
                    if (row < N_NODES)
                        P1a[(long)row * HID + col] = acc[mt][n][r] + bias;
                }
            }
        }
    }

    // ---- stage 2b: P1b = h @ W1b (bf16) ----
    {
        const __bf16* W1b = Wsw + 32768;
        f32x4 acc[2][8] = {};
#pragma unroll
        for (int ks = 0; ks < 4; ++ks) {
            int kb = ks * 32 + quad * 8;
            bf16x8 a0 = *(const bf16x8*)(&At[wave * 32 + r_lane][kb]);
            bf16x8 a1 = *(const bf16x8*)(&At[wave * 32 + 16 + r_lane][kb]);
#pragma unroll
            for (int n = 0; n < 8; ++n) {
                bf16x8 b = *(const bf16x8*)(W1b + ((ks * 8 + n) * 64 + lane) * 8);
                acc[0][n] = __builtin_amdgcn_mfma_f32_16x16x32_bf16(a0, b, acc[0][n], 0, 0, 0);
                acc[1][n] = __builtin_amdgcn_mfma_f32_16x16x32_bf16(a1, b, acc[1][n], 0, 0, 0);
            }
        }
#pragma unroll
        for (int n = 0; n < 8; ++n) {
            int col = n * 16 + r_lane;
#pragma unroll
            for (int mt = 0; mt < 2; ++mt) {
                int rbase = m0 + wave * 32 + mt * 16 + quad * 4;
#pragma unroll
                for (int r = 0; r < 4; ++r) {
                    int row = rbase + r;
                    if (row < N_NODES)
                        P1b[(long)row * HID + col] = (__bf16)acc[mt][n][r];
                }
            }
        }
    }
}

// ---------------------------------------------------------------------------
// scan_a: per-block exclusive scan of hist -> loc, block totals -> bsum
// ---------------------------------------------------------------------------
__global__ __launch_bounds__(256) void scan_a(
    const int* __restrict__ hist, int* __restrict__ loc, int* __restrict__ bsum)
{
    __shared__ int s[256];
    int t = threadIdx.x;
    int i = blockIdx.x * 256 + t;
    int v = (i < N_NODES) ? hist[i] : 0;
    s[t] = v;
    __syncthreads();
    for (int d = 1; d < 256; d <<= 1) {
        int tv = (t >= d) ? s[t - d] : 0;
        __syncthreads();
        s[t] += tv;
        __syncthreads();
    }
    if (i < N_NODES) loc[i] = s[t] - v;
    if (t == 255) bsum[blockIdx.x] = s[255];
}

// scan_c: add inter-block prefix (serial inline, proven R4 pattern)
__global__ __launch_bounds__(256) void scan_c(
    const int* __restrict__ loc, const int* __restrict__ bsum,
    int* __restrict__ offs, int* __restrict__ cursor)
{
    __shared__ int pre;
    if (threadIdx.x == 0) {
        int s = 0;
        for (int b = 0; b < (int)blockIdx.x; ++b) s += bsum[b];
        pre = s;
    }
    __syncthreads();
    int i = blockIdx.x * 256 + threadIdx.x;
    if (i < N_NODES) {
        int o = loc[i] + pre;
        offs[i] = o;
        cursor[i] = o;
    }
}

// permute: scatter src indices into dst-sorted order (dst implied by CSR)
__global__ __launch_bounds__(256) void permute_kernel(
    const int* __restrict__ eidx, int* __restrict__ cursor, int* __restrict__ srt)
{
    int e = blockIdx.x * 256 + threadIdx.x;
    if (e < N_EDGES) {
        int d = eidx[N_EDGES + e];
        int pos = atomicAdd(&cursor[d], 1);
        srt[pos] = eidx[e];
    }
}

// ---------------------------------------------------------------------------
// 8 relu-accumulates of one P1b row (8 bf16 in uint4) against P1a (f32x8)
// ---------------------------------------------------------------------------
__device__ inline void acc8(float4& rA, float4& rB,
                            const float4 paA, const float4 paB, uint4 q)
{
    float t;
    t = paA.x + __uint_as_float(q.x << 16);         rA.x += t > 0.f ? t : 0.f;
    t = paA.y + __uint_as_float(q.x & 0xffff0000u); rA.y += t > 0.f ? t : 0.f;
    t = paA.z + __uint_as_float(q.y << 16);         rA.z += t > 0.f ? t : 0.f;
    t = paA.w + __uint_as_float(q.y & 0xffff0000u); rA.w += t > 0.f ? t : 0.f;
    t = paB.x + __uint_as_float(q.z << 16);         rB.x += t > 0.f ? t : 0.f;
    t = paB.y + __uint_as_float(q.z & 0xffff0000u); rB.y += t > 0.f ? t : 0.f;
    t = paB.z + __uint_as_float(q.w << 16);         rB.z += t > 0.f ? t : 0.f;
    t = paB.w + __uint_as_float(q.w & 0xffff0000u); rB.w += t > 0.f ? t : 0.f;
}

// ---------------------------------------------------------------------------
// aggnode: fused CSR aggregation + node finish. Block = 128 nodes, 512 thr.
// Phase 1: 32 teams x 16 lanes; team aggregates 4 rows into LDS At (bf16),
//          edge loop unrolled x8 -> 8 gathers in flight per lane.
//   At[r] = (bf16) sum_e relu(P1a[node] + P1b[src_e])
// Phase 2: 8 waves, wave w owns 16-row m-tile [16w,16w+16):
//   h2 = relu(At @ W2 + deg*b2); out = h2 @ Wc + bc
// ---------------------------------------------------------------------------
__global__ __launch_bounds__(512) void aggnode_kernel(
    const float* __restrict__ P1a, const __bf16* __restrict__ P1b,
    const int* __restrict__ srt, const int* __restrict__ offs,
    const int* __restrict__ hist, const __bf16* __restrict__ Wsw,
    const float* __restrict__ b2, const float* __restrict__ Wc,
    const float* __restrict__ bc, float* __restrict__ out)
{
    __shared__ __bf16 At[128][136];
    int tid = threadIdx.x;
    int m0 = blockIdx.x * 128;

    // ---- phase 1: aggregate into At ----
    {
        int team = tid >> 4;        // 0..31
        int tl = tid & 15;          // cols [8tl, 8tl+8)
        for (int g = 0; g < 4; ++g) {
            int r = team * 4 + g;
            int node = m0 + r;
            float4 rA = make_float4(0.f, 0.f, 0.f, 0.f);
            float4 rB = make_float4(0.f, 0.f, 0.f, 0.f);
            if (node < N_NODES) {
                int beg = offs[node];
                int deg = hist[node];
                const float* par = P1a + (long)node * HID + tl * 8;
                float4 paA = *(const float4*)par;
                float4 paB = *(const float4*)(par + 4);
                int j = 0;
                for (; j + 8 <= deg; j += 8) {
                    int s0 = srt[beg + j];
                    int s1 = srt[beg + j + 1];
                    int s2 = srt[beg + j + 2];
                    int s3 = srt[beg + j + 3];
                    int s4 = srt[beg + j + 4];
                    int s5 = srt[beg + j + 5];
                    int s6 = srt[beg + j + 6];
                    int s7 = srt[beg + j + 7];
                    uint4 q0 = *(const uint4*)(P1b + (long)s0 * HID + tl * 8);
                    uint4 q1 = *(const uint4*)(P1b + (long)s1 * HID + tl * 8);
                    uint4 q2 = *(const uint4*)(P1b + (long)s2 * HID + tl * 8);
                    uint4 q3 = *(const uint4*)(P1b + (long)s3 * HID + tl * 8);
                    uint4 q4 = *(const uint4*)(P1b + (long)s4 * HID + tl * 8);
                    uint4 q5 = *(const uint4*)(P1b + (long)s5 * HID + tl * 8);
                    uint4 q6 = *(const uint4*)(P1b + (long)s6 * HID + tl * 8);
                    uint4 q7 = *(const uint4*)(P1b + (long)s7 * HID + tl * 8);
                    acc8(rA, rB, paA, paB, q0);
                    acc8(rA, rB, paA, paB, q1);
                    acc8(rA, rB, paA, paB, q2);
                    acc8(rA, rB, paA, paB, q3);
                    acc8(rA, rB, paA, paB, q4);
                    acc8(rA, rB, paA, paB, q5);
                    acc8(rA, rB, paA, paB, q6);
                    acc8(rA, rB, paA, paB, q7);
                }
                for (; j < deg; ++j) {
                    int s = srt[beg + j];
                    uint4 q = *(const uint4*)(P1b + (long)s * HID + tl * 8);
                    acc8(rA, rB, paA, paB, q);
                }
            }
            __bf16 vv[8];
            vv[0] = (__bf16)rA.x; vv[1] = (__bf16)rA.y;
            vv[2] = (__bf16)rA.z; vv[3] = (__bf16)rA.w;
            vv[4] = (__bf16)rB.x; vv[5] = (__bf16)rB.y;
            vv[6] = (__bf16)rB.z; vv[7] = (__bf16)rB.w;
            *(uint4*)(&At[r][tl * 8]) = *(uint4*)vv;
        }
    }
    __syncthreads();

    // ---- phase 2: node GEMM, 8 waves x one 16-row m-tile ----
    int wave = tid >> 6, lane = tid & 63;
    int r_lane = lane & 15, quad = lane >> 4;
    const __bf16* W2f = Wsw + 49152;
    f32x4 acc[8] = {};
#pragma unroll
    for (int ks = 0; ks < 4; ++ks) {
        int kb = ks * 32 + quad * 8;
        bf16x8 a0 = *(const bf16x8*)(&At[wave * 16 + r_lane][kb]);
#pragma unroll
        for (int n = 0; n < 8; ++n) {
            bf16x8 b = *(const bf16x8*)(W2f + ((ks * 8 + n) * 64 + lane) * 8);
            acc[n] = __builtin_amdgcn_mfma_f32_16x16x32_bf16(a0, b, acc[n], 0, 0, 0);
        }
    }

#pragma unroll
    for (int r = 0; r < 4; ++r) {
        int row = m0 + wave * 16 + quad * 4 + r;
        float deg = (row < N_NODES) ? (float)hist[row] : 0.f;
        float s0 = 0.f, s1 = 0.f;
#pragma unroll
        for (int n = 0; n < 8; ++n) {
            int col = n * 16 + r_lane;
            float v = acc[n][r] + deg * b2[col];
            v = v > 0.f ? v : 0.f;
            s0 += v * Wc[col * 2 + 0];
            s1 += v * Wc[col * 2 + 1];
        }
#pragma unroll
        for (int off = 1; off < 16; off <<= 1) {
            s0 += __shfl_xor(s0, off);
            s1 += __shfl_xor(s1, off);
        }
        if (r_lane == 0 && row < N_NODES) {
            out[(long)row * 2 + 0] = s0 + bc[0];
            out[(long)row * 2 + 1] = s1 + bc[1];
        }
    }
}

extern "C" void kernel_launch(void* const* d_in, const int* in_sizes, int n_in,
                              void* d_out, int out_size, void* d_ws, size_t ws_size,
                              hipStream_t stream) {
    const float* x    = (const float*)d_in[0];
    const int* eidx   = (const int*)d_in[1];
    const float* W_in = (const float*)d_in[2];
    const float* b_in = (const float*)d_in[3];
    const float* W1   = (const float*)d_in[4];
    const float* b1   = (const float*)d_in[5];
    const float* W2   = (const float*)d_in[6];
    const float* b2   = (const float*)d_in[7];
    const float* Wc   = (const float*)d_in[8];
    const float* bc   = (const float*)d_in[9];
    float* out = (float*)d_out;

    char* ws = (char*)d_ws;
    float*  P1a  = (float*)(ws + 0);              // 25,600,000
    __bf16* P1b  = (__bf16*)(ws + 25600000);      // 12,800,000
    int* srt     = (int*)(ws + 38400000);         //  3,200,000
    int* hist    = (int*)(ws + 41600000);         //    200,000
    int* loc     = (int*)(ws + 41800000);         //    200,000
    int* offs    = (int*)(ws + 42000000);         //    200,000
    int* cursor  = (int*)(ws + 42200000);         //    200,000
    int* bsum    = (int*)(ws + 42400000);         //      1,024
    __bf16* Wsw  = (__bf16*)(ws + 42401024);      //    131,072

    hipMemsetAsync(hist, 0, (size_t)N_NODES * sizeof(int), stream);

    prep_kernel<<<256 + (N_EDGES + 255) / 256, 256, 0, stream>>>(W_in, W1, W2, Wsw, eidx, hist);
    projp_kernel<<<(N_NODES + 127) / 128, 256, 0, stream>>>(x, Wsw, b_in, b1, P1a, P1b);
    scan_a<<<SCAN_B, 256, 0, stream>>>(hist, loc, bsum);
    scan_c<<<SCAN_B, 256, 0, stream>>>(loc, bsum, offs, cursor);
    permute_kernel<<<(N_EDGES + 255) / 256, 256, 0, stream>>>(eidx, cursor, srt);
    aggnode_kernel<<<(N_NODES + 127) / 128, 512, 0, stream>>>(
        P1a, P1b, srt, offs, hist, Wsw, b2, Wc, bc, out);
}